// Round 1
// baseline (425.590 us; speedup 1.0000x reference)
//
#include <hip/hip_runtime.h>

// FWHT-1024 over rows of a (8*8192, 1024) fp32 tensor, fused with
// out = fwht(x)/sqrt(1024) * scale + shift.
//
// One wave (64 lanes) per row; 16 floats/lane in registers.
// Element e = 256*j + 4*lane + r  (j,r in 0..3) gives:
//   h=1,2     : local in r
//   h=4..128  : __shfl_xor masks 1,2,4,8,16,32 (in-wave, wave=64)
//   h=256,512 : local in j
// No LDS, no barriers. Fully coalesced float4 loads/stores.

constexpr int SIZE = 1024;
constexpr float INV_SQRT = 0.03125f; // 1/sqrt(1024)

__global__ __launch_bounds__(256) void fwht1024_kernel(
    const float* __restrict__ x,
    const float* __restrict__ scale,
    const float* __restrict__ shift,
    float* __restrict__ out,
    int nrows)
{
    const int wave = threadIdx.x >> 6;            // 4 waves per block, 1 row each
    const int lane = threadIdx.x & 63;
    const int row  = blockIdx.x * 4 + wave;
    if (row >= nrows) return;

    const float* __restrict__ xr = x + (size_t)row * SIZE;
    float* __restrict__ orow     = out + (size_t)row * SIZE;

    float v[4][4];
    #pragma unroll
    for (int j = 0; j < 4; ++j) {
        const float4 t = *reinterpret_cast<const float4*>(xr + 256 * j + 4 * lane);
        v[j][0] = t.x; v[j][1] = t.y; v[j][2] = t.z; v[j][3] = t.w;
    }

    // h = 1, 2  (within the r quad)
    #pragma unroll
    for (int j = 0; j < 4; ++j) {
        const float a = v[j][0], b = v[j][1], c = v[j][2], d = v[j][3];
        const float ab = a + b, amb = a - b, cd = c + d, cmd = c - d;
        v[j][0] = ab + cd; v[j][1] = amb + cmd;
        v[j][2] = ab - cd; v[j][3] = amb - cmd;
    }

    // h = 4 .. 128 : cross-lane butterflies, masks 1..32
    #pragma unroll
    for (int m = 1; m <= 32; m <<= 1) {
        const bool upper = (lane & m) != 0;
        #pragma unroll
        for (int j = 0; j < 4; ++j) {
            #pragma unroll
            for (int r = 0; r < 4; ++r) {
                const float o = __shfl_xor(v[j][r], m, 64);
                v[j][r] = upper ? (o - v[j][r]) : (v[j][r] + o);
            }
        }
    }

    // h = 256, 512  (within the j quad)
    #pragma unroll
    for (int r = 0; r < 4; ++r) {
        const float a = v[0][r], b = v[1][r], c = v[2][r], d = v[3][r];
        const float ab = a + b, amb = a - b, cd = c + d, cmd = c - d;
        v[0][r] = ab + cd; v[1][r] = amb + cmd;
        v[2][r] = ab - cd; v[3][r] = amb - cmd;
    }

    // epilogue: *1/32, scale, shift; coalesced float4 stores
    #pragma unroll
    for (int j = 0; j < 4; ++j) {
        const int base = 256 * j + 4 * lane;
        const float4 sc = *reinterpret_cast<const float4*>(scale + base);
        const float4 sh = *reinterpret_cast<const float4*>(shift + base);
        float4 o;
        o.x = fmaf(v[j][0] * INV_SQRT, sc.x, sh.x);
        o.y = fmaf(v[j][1] * INV_SQRT, sc.y, sh.y);
        o.z = fmaf(v[j][2] * INV_SQRT, sc.z, sh.z);
        o.w = fmaf(v[j][3] * INV_SQRT, sc.w, sh.w);
        *reinterpret_cast<float4*>(orow + base) = o;
    }
}

extern "C" void kernel_launch(void* const* d_in, const int* in_sizes, int n_in,
                              void* d_out, int out_size, void* d_ws, size_t ws_size,
                              hipStream_t stream)
{
    const float* x     = (const float*)d_in[0];
    const float* scale = (const float*)d_in[1];
    const float* shift = (const float*)d_in[2];
    float* out         = (float*)d_out;

    const int nrows = in_sizes[0] / SIZE;        // 65536
    const int blocks = (nrows + 3) / 4;          // 4 rows (waves) per block

    fwht1024_kernel<<<blocks, 256, 0, stream>>>(x, scale, shift, out, nrows);
}